// Round 6
// baseline (183.589 us; speedup 1.0000x reference)
//
#include <hip/hip_runtime.h>

#define L_SEQ 2048
#define KDIM  512

typedef __attribute__((ext_vector_type(8))) short short8v;   // 8 x bf16
typedef __attribute__((ext_vector_type(4))) float f32x4;

static __device__ __forceinline__ short f2b(float f) {
    union { float f; unsigned u; } v; v.f = f;
    unsigned r = v.u + 0x7fffu + ((v.u >> 16) & 1u);
    return (short)(r >> 16);
}

static __device__ __forceinline__ float fast_exp2(float x) {
#if __has_builtin(__builtin_amdgcn_exp2f)
    return __builtin_amdgcn_exp2f(x);
#else
    return exp2f(x);
#endif
}

// async global->LDS DMA, 16B per lane. LDS side is wave-uniform base + lane*16.
static __device__ __forceinline__ void gl2lds16(const short* g, short* l) {
    __builtin_amdgcn_global_load_lds(
        (const __attribute__((address_space(1))) unsigned*)g,
        (__attribute__((address_space(3))) unsigned*)l,
        16, 0, 0);
}

// ---------------------------------------------------------------------------
// Weight convert: w_qkv (1536x512) + w_out (512x512) fp32 -> bf16.
// ---------------------------------------------------------------------------
__global__ __launch_bounds__(256) void conv_w(
    const float* __restrict__ wq, const float* __restrict__ wo,
    short* __restrict__ wqb, short* __restrict__ wob)
{
    const int i = blockIdx.x * 256 + threadIdx.x;      // float4 index
    const int NQ = 1536 * 512 / 4;
    float4 v;
    if (i < NQ) v = ((const float4*)wq)[i];
    else        v = ((const float4*)wo)[i - NQ];
    short4 s;
    s.x = f2b(v.x); s.y = f2b(v.y); s.z = f2b(v.z); s.w = f2b(v.w);
    if (i < NQ) ((short4*)wqb)[i] = s;
    else        ((short4*)wob)[i - NQ] = s;
}

// ---------------------------------------------------------------------------
// Transpose+convert: x [b][c=512][l=2048] fp32 -> xT [b][l][c] bf16.
// ---------------------------------------------------------------------------
__global__ __launch_bounds__(256) void transpose_x(
    const float* __restrict__ x, short* __restrict__ xT)
{
    const int b  = blockIdx.z;
    const int c0 = blockIdx.y * 64;
    const int l0 = blockIdx.x * 64;
    __shared__ __align__(16) float T[64 * 72];
    const int t = threadIdx.x;

#pragma unroll
    for (int j = 0; j < 4; ++j) {
        const int idx = j * 256 + t;
        const int row = idx >> 4, c4 = idx & 15;
        const float4 v = *(const float4*)&x[((size_t)b * KDIM + c0 + row) * L_SEQ + l0 + c4 * 4];
        *(float4*)&T[row * 72 + c4 * 4] = v;
    }
    __syncthreads();

#pragma unroll
    for (int j = 0; j < 2; ++j) {
        const int idx = j * 256 + t;
        const int l = idx >> 3, ch = idx & 7;
        short8v s;
#pragma unroll
        for (int e = 0; e < 8; ++e)
            s[e] = f2b(T[(ch * 8 + e) * 72 + l]);
        *(short8v*)&xT[((size_t)b * L_SEQ + l0 + l) * KDIM + c0 + ch * 8] = s;
    }
}

// ---------------------------------------------------------------------------
// m97-style MFMA "bt" GEMM: C[o][l] = sum_c A[o][c]*B[l][c], bf16 row-major.
// Unpadded LDS tiles, global_load_lds(16B) staging, BK=64.
// EPI 0: tile 128x128 -> QKV epilogue (Q/K [bh][l][d] q-scaled, V [bh][d][l]).
// EPI 1: tile  64x128 -> fp32 C[b][o][l] + bias (512-block grid).
// ---------------------------------------------------------------------------
template<int EPI>
__global__ __launch_bounds__(256) void gemm_bt(
    const short* __restrict__ Ag, const short* __restrict__ Bbase,
    const float* __restrict__ bias,
    short* __restrict__ Qws, short* __restrict__ Kws, short* __restrict__ Vws,
    float* __restrict__ Cout)
{
    constexpr int TO   = (EPI == 0) ? 128 : 64;   // o-tile
    constexpr int WO   = TO / 2;                  // per-wave o
    constexpr int NI   = WO / 16;                 // i-subtiles per wave
    constexpr int CA   = TO * 64 * 2 / 1024;      // A chunks (1KB each)
    constexpr int CB   = 16;                      // B chunks
    constexpr int CPW  = (CA + CB) / 4;           // chunks per wave
    constexpr int SMEM = (EPI == 0) ? 34816 : 24576;

    const int bz = blockIdx.z;
    const int o0 = blockIdx.y * TO;
    const int l0 = blockIdx.x * 128;
    const short* Bg = Bbase + (size_t)bz * L_SEQ * KDIM;

    __shared__ __align__(16) char smem[SMEM];
    short* sA = (short*)smem;                       // [TO][64] unpadded
    short* sB = (short*)(smem + TO * 64 * 2);       // [128][64] unpadded

    const int t    = threadIdx.x;
    const int w    = t >> 6;
    const int lane = t & 63;
    const int quad = lane >> 4;
    const int l16  = lane & 15;
    const int wo   = (w & 1) * WO;
    const int wl   = (w >> 1) * 64;

    f32x4 acc[NI][4];
#pragma unroll
    for (int i = 0; i < NI; ++i)
#pragma unroll
        for (int n = 0; n < 4; ++n) acc[i][n] = (f32x4){0,0,0,0};

    const int lrow = lane >> 3;          // 0..7 within a chunk
    const int lcol = (lane & 7) * 8;     // 8-short column offset

    for (int k0 = 0; k0 < KDIM; k0 += 64) {
#pragma unroll
        for (int p = 0; p < CPW; ++p) {
            const int cid = w * CPW + p;
            if (cid < CA) {
                const int row = cid * 8 + lrow;
                gl2lds16(Ag + (size_t)(o0 + row) * KDIM + k0 + lcol, sA + cid * 512);
            } else {
                const int row = (cid - CA) * 8 + lrow;
                gl2lds16(Bg + (size_t)(l0 + row) * KDIM + k0 + lcol, sB + (cid - CA) * 512);
            }
        }
        __syncthreads();

#pragma unroll
        for (int ks = 0; ks < 2; ++ks) {
            short8v af[NI], bf[4];
#pragma unroll
            for (int i = 0; i < NI; ++i)
                af[i] = *(const short8v*)&sA[(wo + i * 16 + l16) * 64 + ks * 32 + quad * 8];
#pragma unroll
            for (int n = 0; n < 4; ++n)
                bf[n] = *(const short8v*)&sB[(wl + n * 16 + l16) * 64 + ks * 32 + quad * 8];
#pragma unroll
            for (int i = 0; i < NI; ++i)
#pragma unroll
                for (int n = 0; n < 4; ++n)
                    acc[i][n] = __builtin_amdgcn_mfma_f32_16x16x32_bf16(af[i], bf[n], acc[i][n], 0, 0, 0);
        }
        __syncthreads();
    }

    if (EPI == 0) {
        const int type  = o0 >> 9;              // 0=q 1=k 2=v
        const int local = o0 & 511;
        const int bh0   = bz * 8 + (local >> 6);
        // q pre-scaled by DIM_HEAD^-0.5 * log2(e) so attention can use exp2
        const float sc  = (type == 0) ? 0.18033688011112042f : 1.0f;
        short* T = (short*)smem;     // [128][136] = 34816 B

        if (type == 2) {
#pragma unroll
            for (int i = 0; i < NI; ++i)
#pragma unroll
                for (int n = 0; n < 4; ++n)
#pragma unroll
                    for (int r = 0; r < 4; ++r)
                        T[(wo + i * 16 + quad * 4 + r) * 136 + wl + n * 16 + l16] =
                            f2b(acc[i][n][r]);
            __syncthreads();
#pragma unroll
            for (int p = 0; p < 8; ++p) {
                const int idx = p * 256 + t;
                const int o = idx >> 4, c = idx & 15;
                const float4 v = *(const float4*)&T[o * 136 + c * 8];
                short* dst = Vws + ((size_t)(bh0 + (o >> 6)) * 64 + (o & 63)) * L_SEQ + l0 + c * 8;
                *(float4*)dst = v;
            }
        } else {
#pragma unroll
            for (int i = 0; i < NI; ++i)
#pragma unroll
                for (int n = 0; n < 4; ++n) {
                    short4 s;
                    s.x = f2b(acc[i][n][0] * sc);
                    s.y = f2b(acc[i][n][1] * sc);
                    s.z = f2b(acc[i][n][2] * sc);
                    s.w = f2b(acc[i][n][3] * sc);
                    *(short4*)&T[(wl + n * 16 + l16) * 136 + wo + i * 16 + quad * 4] = s;
                }
            __syncthreads();
            short* base = (type == 0) ? Qws : Kws;
#pragma unroll
            for (int p = 0; p < 8; ++p) {
                const int idx = p * 256 + t;
                const int l = idx >> 4, c = idx & 15;
                const float4 v = *(const float4*)&T[l * 136 + c * 8];
                short* dst = base + ((size_t)(bh0 + (c >> 3)) * L_SEQ + l0 + l) * 64 + (c & 7) * 8;
                *(float4*)dst = v;
            }
        }
    } else {
        float* Cb = Cout + (size_t)bz * KDIM * L_SEQ;
#pragma unroll
        for (int i = 0; i < NI; ++i) {
            const int o = o0 + wo + i * 16 + quad * 4;
            float bv[4];
#pragma unroll
            for (int r = 0; r < 4; ++r) bv[r] = bias[o + r];
#pragma unroll
            for (int n = 0; n < 4; ++n) {
                const int l = l0 + wl + n * 16 + l16;
#pragma unroll
                for (int r = 0; r < 4; ++r)
                    Cb[(size_t)(o + r) * L_SEQ + l] = acc[i][n][r] + bv[r];
            }
        }
    }
}

// ---------------------------------------------------------------------------
// MFMA attention, 32 i-rows/wave, double-buffered K/V staging with register
// prefetch -> ONE barrier per j-iter; global latency hidden behind compute.
// Buffer selection via byte offsets (no LDS pointer arrays — addrspacecast
// static initializers don't compile on gfx950).
// ---------------------------------------------------------------------------
__global__ __launch_bounds__(256) void attn_mfma(
    const short* __restrict__ Qws, const short* __restrict__ Kws,
    const short* __restrict__ Vws, short* __restrict__ ao)
{
    const int b  = blockIdx.z;
    const int h  = blockIdx.y;
    const int i0 = blockIdx.x * 128;
    const int bh = b * 8 + h;

    __shared__ __align__(16) char smem[55296];
    // layout: [buf0: K 9216 | V 9216][buf1: K 9216 | V 9216][P 18432]
    short* Pld = (short*)(smem + 36864);   // 4 waves x [32][72]
    float* Old = (float*)smem;             // [128][68] fp32 overlay (epilogue)

    const int t    = threadIdx.x;
    const int w    = t >> 6;
    const int lane = t & 63;
    const int quad = lane >> 4;
    const int l16  = lane & 15;

    const short* Qb = Qws + (size_t)bh * L_SEQ * 64;
    const short* Kb = Kws + (size_t)bh * L_SEQ * 64;
    const short* Vb = Vws + (size_t)bh * 64 * L_SEQ;

    // Persistent Q A-fragments: rows i0 + w*32 + hh*16 + l16
    short8v qa[2][2];
#pragma unroll
    for (int hh = 0; hh < 2; ++hh) {
        const short* qrow = Qb + (size_t)(i0 + w * 32 + hh * 16 + l16) * 64 + quad * 8;
        qa[hh][0] = *(const short8v*)qrow;
        qa[hh][1] = *(const short8v*)(qrow + 32);
    }

    f32x4 oacc[2][4];
#pragma unroll
    for (int hh = 0; hh < 2; ++hh)
#pragma unroll
        for (int n = 0; n < 4; ++n) oacc[hh][n] = (f32x4){0,0,0,0};
    float rsum[2][4] = {{0,0,0,0},{0,0,0,0}};
    short* Pw = Pld + w * 32 * 72;

    // staging geometry: thread covers row r, 16-short chunk c (two float4s)
    const int r = t >> 2, c = t & 3;
    float4 ka, kc, va, vc;

    // prologue: tile j0=0 -> buf0
    {
        short* K0 = (short*)smem;
        short* V0 = (short*)(smem + 9216);
        ka = *(const float4*)(Kb + (size_t)r * 64 + c * 16);
        kc = *(const float4*)(Kb + (size_t)r * 64 + c * 16 + 8);
        va = *(const float4*)(Vb + (size_t)r * L_SEQ + c * 16);
        vc = *(const float4*)(Vb + (size_t)r * L_SEQ + c * 16 + 8);
        *(float4*)&K0[r * 72 + c * 16]     = ka;
        *(float4*)&K0[r * 72 + c * 16 + 8] = kc;
        *(float4*)&V0[r * 72 + c * 16]     = va;
        *(float4*)&V0[r * 72 + c * 16 + 8] = vc;
    }

    int cur = 0;
    for (int j0 = 0; j0 < L_SEQ; j0 += 64) {
        __syncthreads();   // buf[cur] visible to all waves
        const short* Kld = (const short*)(smem + cur * 18432);
        const short* Vld = (const short*)(smem + cur * 18432 + 9216);
        const bool pf = (j0 + 64 < L_SEQ);

        if (pf) {          // issue next tile's loads (latency hidden by compute)
            const int jn = j0 + 64;
            ka = *(const float4*)(Kb + (size_t)(jn + r) * 64 + c * 16);
            kc = *(const float4*)(Kb + (size_t)(jn + r) * 64 + c * 16 + 8);
            va = *(const float4*)(Vb + (size_t)r * L_SEQ + jn + c * 16);
            vc = *(const float4*)(Vb + (size_t)r * L_SEQ + jn + c * 16 + 8);
        }

        // S = Q K^T : K-frag reused for both i-halves
        f32x4 sacc[2][4];
#pragma unroll
        for (int hh = 0; hh < 2; ++hh)
#pragma unroll
            for (int n = 0; n < 4; ++n) sacc[hh][n] = (f32x4){0,0,0,0};
#pragma unroll
        for (int n = 0; n < 4; ++n) {
            short8v kf0 = *(const short8v*)&Kld[(n * 16 + l16) * 72 + quad * 8];
            short8v kf1 = *(const short8v*)&Kld[(n * 16 + l16) * 72 + 32 + quad * 8];
#pragma unroll
            for (int hh = 0; hh < 2; ++hh) {
                sacc[hh][n] = __builtin_amdgcn_mfma_f32_16x16x32_bf16(qa[hh][0], kf0, sacc[hh][n], 0, 0, 0);
                sacc[hh][n] = __builtin_amdgcn_mfma_f32_16x16x32_bf16(qa[hh][1], kf1, sacc[hh][n], 0, 0, 0);
            }
        }

        // p = exp2(s), row-sum, P -> bf16 LDS (per-wave region, no barrier)
#pragma unroll
        for (int hh = 0; hh < 2; ++hh)
#pragma unroll
            for (int n = 0; n < 4; ++n)
#pragma unroll
                for (int rr = 0; rr < 4; ++rr) {
                    const float p = fast_exp2(sacc[hh][n][rr]);
                    rsum[hh][rr] += p;
                    Pw[(hh * 16 + quad * 4 + rr) * 72 + n * 16 + l16] = f2b(p);
                }

        // O += P V : V-frag reused for both i-halves
        short8v pa[2][2];
#pragma unroll
        for (int hh = 0; hh < 2; ++hh) {
            pa[hh][0] = *(const short8v*)&Pw[(hh * 16 + l16) * 72 + quad * 8];
            pa[hh][1] = *(const short8v*)&Pw[(hh * 16 + l16) * 72 + 32 + quad * 8];
        }
#pragma unroll
        for (int n = 0; n < 4; ++n) {
            short8v vf0 = *(const short8v*)&Vld[(n * 16 + l16) * 72 + quad * 8];
            short8v vf1 = *(const short8v*)&Vld[(n * 16 + l16) * 72 + 32 + quad * 8];
#pragma unroll
            for (int hh = 0; hh < 2; ++hh) {
                oacc[hh][n] = __builtin_amdgcn_mfma_f32_16x16x32_bf16(pa[hh][0], vf0, oacc[hh][n], 0, 0, 0);
                oacc[hh][n] = __builtin_amdgcn_mfma_f32_16x16x32_bf16(pa[hh][1], vf1, oacc[hh][n], 0, 0, 0);
            }
        }

        if (pf) {          // write prefetched tile into alternate buffer
            short* Kn = (short*)(smem + (cur ^ 1) * 18432);
            short* Vn = (short*)(smem + (cur ^ 1) * 18432 + 9216);
            *(float4*)&Kn[r * 72 + c * 16]     = ka;
            *(float4*)&Kn[r * 72 + c * 16 + 8] = kc;
            *(float4*)&Vn[r * 72 + c * 16]     = va;
            *(float4*)&Vn[r * 72 + c * 16 + 8] = vc;
        }
        cur ^= 1;
    }

    // Row-sum reduce across the 16 j-lanes of each quad
#pragma unroll
    for (int hh = 0; hh < 2; ++hh)
#pragma unroll
        for (int rr = 0; rr < 4; ++rr) {
#pragma unroll
            for (int m = 1; m < 16; m <<= 1)
                rsum[hh][rr] += __shfl_xor(rsum[hh][rr], m, 64);
            rsum[hh][rr] = 1.0f / rsum[hh][rr];
        }

    __syncthreads();   // all waves done with K/V buffers before Old overlay
#pragma unroll
    for (int hh = 0; hh < 2; ++hh)
#pragma unroll
        for (int n = 0; n < 4; ++n)
#pragma unroll
            for (int rr = 0; rr < 4; ++rr)
                Old[(w * 32 + hh * 16 + quad * 4 + rr) * 68 + n * 16 + l16] =
                    oacc[hh][n][rr] * rsum[hh][rr];
    __syncthreads();
#pragma unroll
    for (int p = 0; p < 8; ++p) {
        const int idx = p * 256 + t;
        const int i = idx >> 4, c4 = idx & 15;
        const float4 v = *(const float4*)&Old[i * 68 + c4 * 4];
        short4 s;
        s.x = f2b(v.x); s.y = f2b(v.y); s.z = f2b(v.z); s.w = f2b(v.w);
        *(short4*)&ao[((size_t)b * L_SEQ + i0 + i) * KDIM + h * 64 + c4 * 4] = s;
    }
}

// ---------------------------------------------------------------------------
extern "C" void kernel_launch(void* const* d_in, const int* in_sizes, int n_in,
                              void* d_out, int out_size, void* d_ws, size_t ws_size,
                              hipStream_t stream)
{
    const float* x     = (const float*)d_in[0];   // [4][512][2048]
    const float* w_qkv = (const float*)d_in[1];   // [1536][512]
    const float* w_out = (const float*)d_in[2];   // [512][512]
    const float* b_out = (const float*)d_in[3];   // [512]
    float* out = (float*)d_out;                   // [4][512][2048]

    char* ws = (char*)d_ws;
    short* xT    = (short*)ws;                      ws += (size_t)4 * L_SEQ * KDIM * 2;
    short* wq_bf = (short*)ws;                      ws += (size_t)1536 * 512 * 2;
    short* wo_bf = (short*)ws;                      ws += (size_t)512 * 512 * 2;
    short* Qws   = (short*)ws;                      ws += (size_t)32 * L_SEQ * 64 * 2;
    short* Kws   = (short*)ws;                      ws += (size_t)32 * L_SEQ * 64 * 2;
    short* Vws   = (short*)ws;                      ws += (size_t)32 * L_SEQ * 64 * 2;
    short* ao    = (short*)ws;

    dim3 blk(256);
    conv_w     <<<dim3(1024), blk, 0, stream>>>(w_qkv, w_out, wq_bf, wo_bf);
    transpose_x<<<dim3(32, 8, 4), blk, 0, stream>>>(x, xT);
    gemm_bt<0> <<<dim3(16, 12, 4), blk, 0, stream>>>(wq_bf, xT, nullptr, Qws, Kws, Vws, nullptr);
    attn_mfma  <<<dim3(16, 8, 4), blk, 0, stream>>>(Qws, Kws, Vws, ao);
    gemm_bt<1> <<<dim3(16, 8, 4), blk, 0, stream>>>(wo_bf, ao, b_out, nullptr, nullptr, nullptr, out);
}

// Round 7
// 168.664 us; speedup vs baseline: 1.0885x; 1.0885x over previous
//
#include <hip/hip_runtime.h>

#define L_SEQ 2048
#define KDIM  512

typedef __attribute__((ext_vector_type(8))) short short8v;   // 8 x bf16
typedef __attribute__((ext_vector_type(4))) float f32x4;

static __device__ __forceinline__ short f2b(float f) {
    union { float f; unsigned u; } v; v.f = f;
    unsigned r = v.u + 0x7fffu + ((v.u >> 16) & 1u);
    return (short)(r >> 16);
}

static __device__ __forceinline__ float fast_exp2(float x) {
#if __has_builtin(__builtin_amdgcn_exp2f)
    return __builtin_amdgcn_exp2f(x);
#else
    return exp2f(x);
#endif
}

// async global->LDS DMA, 16B per lane. LDS side is wave-uniform base + lane*16.
static __device__ __forceinline__ void gl2lds16(const short* g, short* l) {
    __builtin_amdgcn_global_load_lds(
        (const __attribute__((address_space(1))) unsigned*)g,
        (__attribute__((address_space(3))) unsigned*)l,
        16, 0, 0);
}

// ---------------------------------------------------------------------------
// prep: (blocks 0..1023)  w_qkv + w_out fp32 -> bf16
//       (blocks 1024..2047) x [b][c][l] fp32 -> xT [b][l][c] bf16
// ---------------------------------------------------------------------------
__global__ __launch_bounds__(256) void prep(
    const float* __restrict__ wq, const float* __restrict__ wo,
    const float* __restrict__ x,
    short* __restrict__ wqb, short* __restrict__ wob, short* __restrict__ xT)
{
    __shared__ __align__(16) float T[64 * 72];
    const int t = threadIdx.x;
    int bid = blockIdx.x;

    if (bid < 1024) {
        const int i = bid * 256 + t;               // float4 index
        const int NQ = 1536 * 512 / 4;
        float4 v;
        if (i < NQ) v = ((const float4*)wq)[i];
        else        v = ((const float4*)wo)[i - NQ];
        short4 s;
        s.x = f2b(v.x); s.y = f2b(v.y); s.z = f2b(v.z); s.w = f2b(v.w);
        if (i < NQ) ((short4*)wqb)[i] = s;
        else        ((short4*)wob)[i - NQ] = s;
        return;
    }
    bid -= 1024;
    const int l0 = (bid & 31) * 64;
    const int c0 = ((bid >> 5) & 7) * 64;
    const int b  = bid >> 8;

#pragma unroll
    for (int j = 0; j < 4; ++j) {
        const int idx = j * 256 + t;
        const int row = idx >> 4, c4 = idx & 15;
        const float4 v = *(const float4*)&x[((size_t)b * KDIM + c0 + row) * L_SEQ + l0 + c4 * 4];
        *(float4*)&T[row * 72 + c4 * 4] = v;
    }
    __syncthreads();

#pragma unroll
    for (int j = 0; j < 2; ++j) {
        const int idx = j * 256 + t;
        const int l = idx >> 3, ch = idx & 7;
        short8v s;
#pragma unroll
        for (int e = 0; e < 8; ++e)
            s[e] = f2b(T[(ch * 8 + e) * 72 + l]);
        *(short8v*)&xT[((size_t)b * L_SEQ + l0 + l) * KDIM + c0 + ch * 8] = s;
    }
}

// ---------------------------------------------------------------------------
// m97-style MFMA "bt" GEMM: C[o][l] = sum_c A[o][c]*B[l][c], bf16 row-major.
// Unpadded LDS tiles, global_load_lds(16B) staging, BK=64.
// EPI 0: tile 128x128 -> QKV epilogue (Q/K [bh][l][d] q-scaled, V [bh][d][l]).
// EPI 1: tile  64x128 -> fp32 C[b][o][l] + bias (512-block grid).
// ---------------------------------------------------------------------------
template<int EPI>
__global__ __launch_bounds__(256) void gemm_bt(
    const short* __restrict__ Ag, const short* __restrict__ Bbase,
    const float* __restrict__ bias,
    short* __restrict__ Qws, short* __restrict__ Kws, short* __restrict__ Vws,
    float* __restrict__ Cout)
{
    constexpr int TO   = (EPI == 0) ? 128 : 64;   // o-tile
    constexpr int WO   = TO / 2;                  // per-wave o
    constexpr int NI   = WO / 16;                 // i-subtiles per wave
    constexpr int CA   = TO * 64 * 2 / 1024;      // A chunks (1KB each)
    constexpr int CB   = 16;                      // B chunks
    constexpr int CPW  = (CA + CB) / 4;           // chunks per wave
    constexpr int SMEM = (EPI == 0) ? 34816 : 24576;

    const int bz = blockIdx.z;
    const int o0 = blockIdx.y * TO;
    const int l0 = blockIdx.x * 128;
    const short* Bg = Bbase + (size_t)bz * L_SEQ * KDIM;

    __shared__ __align__(16) char smem[SMEM];
    short* sA = (short*)smem;                       // [TO][64] unpadded
    short* sB = (short*)(smem + TO * 64 * 2);       // [128][64] unpadded

    const int t    = threadIdx.x;
    const int w    = t >> 6;
    const int lane = t & 63;
    const int quad = lane >> 4;
    const int l16  = lane & 15;
    const int wo   = (w & 1) * WO;
    const int wl   = (w >> 1) * 64;

    f32x4 acc[NI][4];
#pragma unroll
    for (int i = 0; i < NI; ++i)
#pragma unroll
        for (int n = 0; n < 4; ++n) acc[i][n] = (f32x4){0,0,0,0};

    const int lrow = lane >> 3;          // 0..7 within a chunk
    const int lcol = (lane & 7) * 8;     // 8-short column offset

    for (int k0 = 0; k0 < KDIM; k0 += 64) {
#pragma unroll
        for (int p = 0; p < CPW; ++p) {
            const int cid = w * CPW + p;
            if (cid < CA) {
                const int row = cid * 8 + lrow;
                gl2lds16(Ag + (size_t)(o0 + row) * KDIM + k0 + lcol, sA + cid * 512);
            } else {
                const int row = (cid - CA) * 8 + lrow;
                gl2lds16(Bg + (size_t)(l0 + row) * KDIM + k0 + lcol, sB + (cid - CA) * 512);
            }
        }
        __syncthreads();

#pragma unroll
        for (int ks = 0; ks < 2; ++ks) {
            short8v af[NI], bf[4];
#pragma unroll
            for (int i = 0; i < NI; ++i)
                af[i] = *(const short8v*)&sA[(wo + i * 16 + l16) * 64 + ks * 32 + quad * 8];
#pragma unroll
            for (int n = 0; n < 4; ++n)
                bf[n] = *(const short8v*)&sB[(wl + n * 16 + l16) * 64 + ks * 32 + quad * 8];
#pragma unroll
            for (int i = 0; i < NI; ++i)
#pragma unroll
                for (int n = 0; n < 4; ++n)
                    acc[i][n] = __builtin_amdgcn_mfma_f32_16x16x32_bf16(af[i], bf[n], acc[i][n], 0, 0, 0);
        }
        __syncthreads();
    }

    if (EPI == 0) {
        const int type  = o0 >> 9;              // 0=q 1=k 2=v
        const int local = o0 & 511;
        const int bh0   = bz * 8 + (local >> 6);
        // q pre-scaled by DIM_HEAD^-0.5 * log2(e) so attention can use exp2
        const float sc  = (type == 0) ? 0.18033688011112042f : 1.0f;
        short* T = (short*)smem;     // [128][136] = 34816 B

        if (type == 2) {
#pragma unroll
            for (int i = 0; i < NI; ++i)
#pragma unroll
                for (int n = 0; n < 4; ++n)
#pragma unroll
                    for (int r = 0; r < 4; ++r)
                        T[(wo + i * 16 + quad * 4 + r) * 136 + wl + n * 16 + l16] =
                            f2b(acc[i][n][r]);
            __syncthreads();
#pragma unroll
            for (int p = 0; p < 8; ++p) {
                const int idx = p * 256 + t;
                const int o = idx >> 4, c = idx & 15;
                const float4 v = *(const float4*)&T[o * 136 + c * 8];
                short* dst = Vws + ((size_t)(bh0 + (o >> 6)) * 64 + (o & 63)) * L_SEQ + l0 + c * 8;
                *(float4*)dst = v;
            }
        } else {
#pragma unroll
            for (int i = 0; i < NI; ++i)
#pragma unroll
                for (int n = 0; n < 4; ++n) {
                    short4 s;
                    s.x = f2b(acc[i][n][0] * sc);
                    s.y = f2b(acc[i][n][1] * sc);
                    s.z = f2b(acc[i][n][2] * sc);
                    s.w = f2b(acc[i][n][3] * sc);
                    *(short4*)&T[(wl + n * 16 + l16) * 136 + wo + i * 16 + quad * 4] = s;
                }
            __syncthreads();
            short* base = (type == 0) ? Qws : Kws;
#pragma unroll
            for (int p = 0; p < 8; ++p) {
                const int idx = p * 256 + t;
                const int l = idx >> 4, c = idx & 15;
                const float4 v = *(const float4*)&T[l * 136 + c * 8];
                short* dst = base + ((size_t)(bh0 + (c >> 3)) * L_SEQ + l0 + l) * 64 + (c & 7) * 8;
                *(float4*)dst = v;
            }
        }
    } else {
        float* Cb = Cout + (size_t)bz * KDIM * L_SEQ;
#pragma unroll
        for (int i = 0; i < NI; ++i) {
            const int o = o0 + wo + i * 16 + quad * 4;
            float bv[4];
#pragma unroll
            for (int r = 0; r < 4; ++r) bv[r] = bias[o + r];
#pragma unroll
            for (int n = 0; n < 4; ++n) {
                const int l = l0 + wl + n * 16 + l16;
#pragma unroll
                for (int r = 0; r < 4; ++r)
                    Cb[(size_t)(o + r) * L_SEQ + l] = acc[i][n][r] + bv[r];
            }
        }
    }
}

// ---------------------------------------------------------------------------
// MFMA attention. 32 i-rows/wave, 128/block. S^T = K*Q^T (operand swap) so
// the C-frag regs are j-contiguous: P packs 2 bf16/instr via v_perm_b32
// (truncation; bias folded into 1/rsum) and stores ds_write_b64. Row-sums are
// per-lane scalars (i = l16). XCD swizzle: bh = id&31 -> same-head blocks on
// one XCD (K/V stays in that XCD's 4MB L2).
// ---------------------------------------------------------------------------
__global__ __launch_bounds__(256) void attn_mfma(
    const short* __restrict__ Qws, const short* __restrict__ Kws,
    const short* __restrict__ Vws, short* __restrict__ ao)
{
    const int bh = blockIdx.x & 31;
    const int b  = bh >> 3;
    const int h  = bh & 7;
    const int i0 = (blockIdx.x >> 5) * 128;

    __shared__ __align__(16) char smem[36864];
    short* Kld = (short*)smem;             // [64 j][72 d]
    short* Vld = (short*)(smem + 9216);    // [64 d][72 j]
    short* Pld = (short*)(smem + 18432);   // 4 waves x [32 i][72 j]
    float* Old = (float*)smem;             // [128 i][68 d] fp32 overlay (epilogue)

    const int t    = threadIdx.x;
    const int w    = t >> 6;
    const int lane = t & 63;
    const int quad = lane >> 4;
    const int l16  = lane & 15;

    const short* Qb = Qws + (size_t)bh * L_SEQ * 64;
    const short* Kb = Kws + (size_t)bh * L_SEQ * 64;
    const short* Vb = Vws + (size_t)bh * 64 * L_SEQ;

    // Persistent Q fragments (B-operand for S^T; same reg layout as A-frag)
    short8v qa[2][2];
#pragma unroll
    for (int hh = 0; hh < 2; ++hh) {
        const short* qrow = Qb + (size_t)(i0 + w * 32 + hh * 16 + l16) * 64 + quad * 8;
        qa[hh][0] = *(const short8v*)qrow;
        qa[hh][1] = *(const short8v*)(qrow + 32);
    }

    f32x4 oacc[2][4];
#pragma unroll
    for (int hh = 0; hh < 2; ++hh)
#pragma unroll
        for (int n = 0; n < 4; ++n) oacc[hh][n] = (f32x4){0,0,0,0};
    float rsum[2] = {0.f, 0.f};
    short* Pw = Pld + w * 32 * 72;

    const int r = t >> 2, c = t & 3;

    for (int j0 = 0; j0 < L_SEQ; j0 += 64) {
        // Stage K tile [j][d] and V^T tile [d][j]
        {
            const float4 k0 = *(const float4*)(Kb + (size_t)(j0 + r) * 64 + c * 16);
            const float4 k1 = *(const float4*)(Kb + (size_t)(j0 + r) * 64 + c * 16 + 8);
            const float4 v0 = *(const float4*)(Vb + (size_t)r * L_SEQ + j0 + c * 16);
            const float4 v1 = *(const float4*)(Vb + (size_t)r * L_SEQ + j0 + c * 16 + 8);
            *(float4*)&Kld[r * 72 + c * 16]     = k0;
            *(float4*)&Kld[r * 72 + c * 16 + 8] = k1;
            *(float4*)&Vld[r * 72 + c * 16]     = v0;
            *(float4*)&Vld[r * 72 + c * 16 + 8] = v1;
        }
        __syncthreads();

        // S^T = K Q^T : C-frag lane holds col=i=l16, rows=j (contiguous regs)
        f32x4 sacc[2][4];
#pragma unroll
        for (int hh = 0; hh < 2; ++hh)
#pragma unroll
            for (int n = 0; n < 4; ++n) sacc[hh][n] = (f32x4){0,0,0,0};
#pragma unroll
        for (int n = 0; n < 4; ++n) {
            short8v kf0 = *(const short8v*)&Kld[(n * 16 + l16) * 72 + quad * 8];
            short8v kf1 = *(const short8v*)&Kld[(n * 16 + l16) * 72 + 32 + quad * 8];
#pragma unroll
            for (int hh = 0; hh < 2; ++hh) {
                sacc[hh][n] = __builtin_amdgcn_mfma_f32_16x16x32_bf16(kf0, qa[hh][0], sacc[hh][n], 0, 0, 0);
                sacc[hh][n] = __builtin_amdgcn_mfma_f32_16x16x32_bf16(kf1, qa[hh][1], sacc[hh][n], 0, 0, 0);
            }
        }

        // p = exp2(s); per-lane rsum (i = l16); pack pairs (v_perm) + b64 store
#pragma unroll
        for (int hh = 0; hh < 2; ++hh)
#pragma unroll
            for (int n = 0; n < 4; ++n) {
                const float p0 = fast_exp2(sacc[hh][n][0]);
                const float p1 = fast_exp2(sacc[hh][n][1]);
                const float p2 = fast_exp2(sacc[hh][n][2]);
                const float p3 = fast_exp2(sacc[hh][n][3]);
                rsum[hh] += (p0 + p1) + (p2 + p3);
                uint2 pv;
                pv.x = __builtin_amdgcn_perm(__float_as_uint(p1), __float_as_uint(p0), 0x07060302u);
                pv.y = __builtin_amdgcn_perm(__float_as_uint(p3), __float_as_uint(p2), 0x07060302u);
                *(uint2*)&Pw[(hh * 16 + l16) * 72 + n * 16 + quad * 4] = pv;
            }

        // O += P V : A = P[i][j] (b128 reads), B = V^T rows
        short8v pa[2][2];
#pragma unroll
        for (int hh = 0; hh < 2; ++hh) {
            pa[hh][0] = *(const short8v*)&Pw[(hh * 16 + l16) * 72 + quad * 8];
            pa[hh][1] = *(const short8v*)&Pw[(hh * 16 + l16) * 72 + 32 + quad * 8];
        }
#pragma unroll
        for (int n = 0; n < 4; ++n) {
            short8v vf0 = *(const short8v*)&Vld[(n * 16 + l16) * 72 + quad * 8];
            short8v vf1 = *(const short8v*)&Vld[(n * 16 + l16) * 72 + 32 + quad * 8];
#pragma unroll
            for (int hh = 0; hh < 2; ++hh) {
                oacc[hh][n] = __builtin_amdgcn_mfma_f32_16x16x32_bf16(pa[hh][0], vf0, oacc[hh][n], 0, 0, 0);
                oacc[hh][n] = __builtin_amdgcn_mfma_f32_16x16x32_bf16(pa[hh][1], vf1, oacc[hh][n], 0, 0, 0);
            }
        }
        __syncthreads();
    }

    // Reduce rsum across quads (lanes share i = l16); truncation-bias comp.
    float inv[2];
#pragma unroll
    for (int hh = 0; hh < 2; ++hh) {
        rsum[hh] += __shfl_xor(rsum[hh], 16, 64);
        rsum[hh] += __shfl_xor(rsum[hh], 32, 64);
        inv[hh] = 1.0014f / rsum[hh];
    }

    // Normalize (inv fetched cross-lane), stage [i][d] in LDS, bf16 stores
#pragma unroll
    for (int hh = 0; hh < 2; ++hh)
#pragma unroll
        for (int rr = 0; rr < 4; ++rr) {
            const float iv = __shfl(inv[hh], quad * 4 + rr, 64);
#pragma unroll
            for (int n = 0; n < 4; ++n)
                Old[(w * 32 + hh * 16 + quad * 4 + rr) * 68 + n * 16 + l16] =
                    oacc[hh][n][rr] * iv;
        }
    __syncthreads();
#pragma unroll
    for (int p = 0; p < 8; ++p) {
        const int idx = p * 256 + t;
        const int i = idx >> 4, c4 = idx & 15;
        const float4 v = *(const float4*)&Old[i * 68 + c4 * 4];
        short4 s;
        s.x = f2b(v.x); s.y = f2b(v.y); s.z = f2b(v.z); s.w = f2b(v.w);
        *(short4*)&ao[((size_t)b * L_SEQ + i0 + i) * KDIM + h * 64 + c4 * 4] = s;
    }
}

// ---------------------------------------------------------------------------
extern "C" void kernel_launch(void* const* d_in, const int* in_sizes, int n_in,
                              void* d_out, int out_size, void* d_ws, size_t ws_size,
                              hipStream_t stream)
{
    const float* x     = (const float*)d_in[0];   // [4][512][2048]
    const float* w_qkv = (const float*)d_in[1];   // [1536][512]
    const float* w_out = (const float*)d_in[2];   // [512][512]
    const float* b_out = (const float*)d_in[3];   // [512]
    float* out = (float*)d_out;                   // [4][512][2048]

    char* ws = (char*)d_ws;
    short* xT    = (short*)ws;                      ws += (size_t)4 * L_SEQ * KDIM * 2;
    short* wq_bf = (short*)ws;                      ws += (size_t)1536 * 512 * 2;
    short* wo_bf = (short*)ws;                      ws += (size_t)512 * 512 * 2;
    short* Qws   = (short*)ws;                      ws += (size_t)32 * L_SEQ * 64 * 2;
    short* Kws   = (short*)ws;                      ws += (size_t)32 * L_SEQ * 64 * 2;
    short* Vws   = (short*)ws;                      ws += (size_t)32 * L_SEQ * 64 * 2;
    short* ao    = (short*)ws;

    dim3 blk(256);
    prep       <<<dim3(2048), blk, 0, stream>>>(w_qkv, w_out, x, wq_bf, wo_bf, xT);
    gemm_bt<0> <<<dim3(16, 12, 4), blk, 0, stream>>>(wq_bf, xT, nullptr, Qws, Kws, Vws, nullptr);
    attn_mfma  <<<dim3(512), blk, 0, stream>>>(Qws, Kws, Vws, ao);
    gemm_bt<1> <<<dim3(16, 8, 4), blk, 0, stream>>>(wo_bf, ao, b_out, nullptr, nullptr, nullptr, out);
}